// Round 1
// baseline (103670.251 us; speedup 1.0000x reference)
//
#include <hip/hip_runtime.h>
#include <hip/hip_bf16.h>
#include <cstdint>
#include <cstddef>

// Problem constants
#define T_STEPS 8192
#define IN_DIM  1024
#define HID     1024
#define OUT_DIM 1024
#define G4      4096   // 4*HID

// Recurrence kernel geometry: 64 blocks x 256 threads = 256 waves,
// each wave owns 4 hidden units (i,f,g,o rows for each) -> 16 rows of W_h,
// 16 fp32 weights per lane per row -> w[16][16] = 256 VGPRs (OK at 1 wave/SIMD).
#define NBLK 64
#define TPB  256
#define UPW  4   // hidden units per wave

__device__ __forceinline__ float sigf(float x) {
  return 1.0f / (1.0f + __expf(-x));
}
__device__ __forceinline__ float tanh_fast(float x) {
  float e = __expf(-2.0f * fabsf(x));
  float t = (1.0f - e) / (1.0f + e);
  return copysignf(t, x);
}

// Device-wide barrier: agent-scope atomics, generation-counted.
// Safe because all NBLK blocks are guaranteed co-resident (64 blocks <= 256 CUs,
// one 256-thread block needs only 4 waves / 1 per SIMD).
__device__ __forceinline__ void grid_barrier(unsigned* cnt, unsigned* gen) {
  __syncthreads();   // all block's stores drained to L2 (s_waitcnt vmcnt(0) before s_barrier)
  if (threadIdx.x == 0) {
    unsigned g = __hip_atomic_load(gen, __ATOMIC_RELAXED, __HIP_MEMORY_SCOPE_AGENT);
    unsigned arr = __hip_atomic_fetch_add(cnt, 1u, __ATOMIC_ACQ_REL, __HIP_MEMORY_SCOPE_AGENT);
    if (arr == NBLK - 1) {
      __hip_atomic_store(cnt, 0u, __ATOMIC_RELAXED, __HIP_MEMORY_SCOPE_AGENT);
      __hip_atomic_fetch_add(gen, 1u, __ATOMIC_ACQ_REL, __HIP_MEMORY_SCOPE_AGENT);
    } else {
      while (__hip_atomic_load(gen, __ATOMIC_ACQUIRE, __HIP_MEMORY_SCOPE_AGENT) == g) {
        __builtin_amdgcn_s_sleep(1);
      }
    }
  }
  __syncthreads();
}

// ---------------------------------------------------------------------------
// GEMM: C[M,N] = A[M,K] @ B[N,K]^T + bias[N]   (both operands row-major over K)
// 64x64 block tile, TK=16, 256 threads, 4x4 microtile. M,N,K all multiples of
// tile sizes here (8192 / {4096,1024} / 1024) -> no bounds checks.
// ---------------------------------------------------------------------------
__global__ __launch_bounds__(256) void gemm_nt(
    const float* __restrict__ A, int lda,
    const float* __restrict__ B, int ldb,
    const float* __restrict__ bias,
    float* __restrict__ C, int ldc,
    int K)
{
  __shared__ float As[16][72];  // pad 72: float4-aligned rows (288B), conflict-light
  __shared__ float Bs[16][72];

  const int tid = threadIdx.x;
  const int m0 = blockIdx.y * 64;
  const int n0 = blockIdx.x * 64;
  const int lr = tid >> 2;         // 0..63 : tile row loaded by this thread
  const int lk = (tid & 3) * 4;    // 0,4,8,12 : k-offset of its float4
  const int ty = tid >> 4;         // 0..15 : C row group
  const int tx = tid & 15;         // 0..15 : C col group

  float acc[4][4];
#pragma unroll
  for (int i = 0; i < 4; ++i)
#pragma unroll
    for (int j = 0; j < 4; ++j) acc[i][j] = 0.0f;

  const float* Ag = A + (size_t)(m0 + lr) * lda + lk;
  const float* Bg = B + (size_t)(n0 + lr) * ldb + lk;

  for (int kt = 0; kt < K; kt += 16) {
    float4 av = *(const float4*)(Ag + kt);
    float4 bv = *(const float4*)(Bg + kt);
    __syncthreads();
    As[lk + 0][lr] = av.x; As[lk + 1][lr] = av.y;
    As[lk + 2][lr] = av.z; As[lk + 3][lr] = av.w;
    Bs[lk + 0][lr] = bv.x; Bs[lk + 1][lr] = bv.y;
    Bs[lk + 2][lr] = bv.z; Bs[lk + 3][lr] = bv.w;
    __syncthreads();
#pragma unroll
    for (int k = 0; k < 16; ++k) {
      float4 a4 = *(const float4*)&As[k][ty * 4];
      float4 b4 = *(const float4*)&Bs[k][tx * 4];
      acc[0][0] = fmaf(a4.x, b4.x, acc[0][0]); acc[0][1] = fmaf(a4.x, b4.y, acc[0][1]);
      acc[0][2] = fmaf(a4.x, b4.z, acc[0][2]); acc[0][3] = fmaf(a4.x, b4.w, acc[0][3]);
      acc[1][0] = fmaf(a4.y, b4.x, acc[1][0]); acc[1][1] = fmaf(a4.y, b4.y, acc[1][1]);
      acc[1][2] = fmaf(a4.y, b4.z, acc[1][2]); acc[1][3] = fmaf(a4.y, b4.w, acc[1][3]);
      acc[2][0] = fmaf(a4.z, b4.x, acc[2][0]); acc[2][1] = fmaf(a4.z, b4.y, acc[2][1]);
      acc[2][2] = fmaf(a4.z, b4.z, acc[2][2]); acc[2][3] = fmaf(a4.z, b4.w, acc[2][3]);
      acc[3][0] = fmaf(a4.w, b4.x, acc[3][0]); acc[3][1] = fmaf(a4.w, b4.y, acc[3][1]);
      acc[3][2] = fmaf(a4.w, b4.z, acc[3][2]); acc[3][3] = fmaf(a4.w, b4.w, acc[3][3]);
    }
  }

  float4 b4 = *(const float4*)(bias + n0 + tx * 4);
#pragma unroll
  for (int i = 0; i < 4; ++i) {
    float4 o;
    o.x = acc[i][0] + b4.x; o.y = acc[i][1] + b4.y;
    o.z = acc[i][2] + b4.z; o.w = acc[i][3] + b4.w;
    *(float4*)(C + (size_t)(m0 + ty * 4 + i) * ldc + n0 + tx * 4) = o;
  }
}

// ---------------------------------------------------------------------------
// Persistent recurrence kernel. pre = x@Wx^T + b precomputed ([T,4096]).
// Each wave: 4 hidden units; weights W_h rows held in VGPRs for all 8192 steps.
// h double-buffered in global; device barrier per step.
// ---------------------------------------------------------------------------
__global__ __launch_bounds__(TPB, 1) void lstm_rec(
    const float* __restrict__ Ww,    // [4096, 2048]
    const float* __restrict__ pre,   // [T, 4096]
    float* __restrict__ hbuf,        // [2, 1024]
    float* __restrict__ hall,        // [T, 1024]
    unsigned* __restrict__ bar)      // {cnt, gen}
{
  const int lane = threadIdx.x & 63;
  const int wv = blockIdx.x * (TPB / 64) + (threadIdx.x >> 6);  // 0..255
  const int u0 = wv * UPW;                                      // first hidden unit

  // Load persistent weights: row m = ul*4+g  <->  W_w row (g*HID + u0+ul), h-part cols.
  float w[16][16];
#pragma unroll
  for (int ul = 0; ul < UPW; ++ul) {
#pragma unroll
    for (int g = 0; g < 4; ++g) {
      const int m = ul * 4 + g;
      const float* wr = Ww + (size_t)(g * HID + u0 + ul) * (IN_DIM + HID) + IN_DIM + lane * 16;
#pragma unroll
      for (int q = 0; q < 4; ++q) {
        float4 v = *(const float4*)(wr + q * 4);
        w[m][q * 4 + 0] = v.x; w[m][q * 4 + 1] = v.y;
        w[m][q * 4 + 2] = v.z; w[m][q * 4 + 3] = v.w;
      }
    }
  }

  float cst[UPW];
#pragma unroll
  for (int ul = 0; ul < UPW; ++ul) cst[ul] = 0.0f;

  unsigned* cnt = bar;
  unsigned* gen = bar + 1;

  for (int t = 0; t < T_STEPS; ++t) {
    // gather h_{t-1}: this lane's 16 contiguous elements
    const float* hp = hbuf + (size_t)(t & 1) * HID + lane * 16;
    float hv[16];
#pragma unroll
    for (int q = 0; q < 4; ++q) {
      float4 v = *(const float4*)(hp + q * 4);
      hv[q * 4 + 0] = v.x; hv[q * 4 + 1] = v.y;
      hv[q * 4 + 2] = v.z; hv[q * 4 + 3] = v.w;
    }

    float acc[16];
#pragma unroll
    for (int m = 0; m < 16; ++m) acc[m] = 0.0f;
#pragma unroll
    for (int e = 0; e < 16; ++e)
#pragma unroll
      for (int m = 0; m < 16; ++m)
        acc[m] = fmaf(w[m][e], hv[e], acc[m]);

    // full-wave butterfly reduce: every lane ends with all 16 row sums
#pragma unroll
    for (int m = 0; m < 16; ++m) {
      float v = acc[m];
      v += __shfl_xor(v, 1);  v += __shfl_xor(v, 2);  v += __shfl_xor(v, 4);
      v += __shfl_xor(v, 8);  v += __shfl_xor(v, 16); v += __shfl_xor(v, 32);
      acc[m] = v;
    }

    const float* pr = pre + (size_t)t * G4 + u0;
    float hval[UPW];
#pragma unroll
    for (int ul = 0; ul < UPW; ++ul) {
      float gi = acc[ul * 4 + 0] + pr[0 * HID + ul];
      float gf = acc[ul * 4 + 1] + pr[1 * HID + ul];
      float gg = acc[ul * 4 + 2] + pr[2 * HID + ul];
      float go = acc[ul * 4 + 3] + pr[3 * HID + ul];
      cst[ul] = sigf(gf) * cst[ul] + sigf(gi) * tanh_fast(gg);
      hval[ul] = sigf(go) * tanh_fast(cst[ul]);
    }

    if (lane == 0) {
      float* hw = hbuf + (size_t)((t + 1) & 1) * HID + u0;
      float* hr = hall + (size_t)t * HID + u0;
#pragma unroll
      for (int ul = 0; ul < UPW; ++ul) { hw[ul] = hval[ul]; hr[ul] = hval[ul]; }
    }

    grid_barrier(cnt, gen);
  }
}

// ---------------------------------------------------------------------------
// Workspace layout (bytes):
//   [0,8)                : barrier {cnt, gen}
//   [256, 256+8K)        : hbuf[2][1024]
//   [16384, +33.5MB)     : hall[T][1024]
//   [16384+33.5MB, +134MB): pre[T][4096]
// total ~161 MB
// ---------------------------------------------------------------------------
extern "C" void kernel_launch(void* const* d_in, const int* in_sizes, int n_in,
                              void* d_out, int out_size, void* d_ws, size_t ws_size,
                              hipStream_t stream) {
  (void)in_sizes; (void)n_in; (void)out_size; (void)ws_size;

  const float* x     = (const float*)d_in[0];  // [T,1,IN]
  const float* W_w   = (const float*)d_in[1];  // [4096, 2048]
  const float* W_b   = (const float*)d_in[2];  // [4096]
  const float* out_w = (const float*)d_in[3];  // [1024, 1024]
  const float* out_b = (const float*)d_in[4];  // [1024]
  float* out = (float*)d_out;                  // [T,1,1024]

  char* ws = (char*)d_ws;
  unsigned* bar = (unsigned*)(ws + 0);
  float* hbuf   = (float*)(ws + 256);
  float* hall   = (float*)(ws + 16384);
  float* pre    = (float*)(ws + 16384 + (size_t)T_STEPS * HID * 4);

  // zero barrier + h0 double buffer (ws is poisoned 0xAA before every call)
  hipMemsetAsync(ws, 0, 16384, stream);

  // pre = x @ Wx^T + W_b   (Wx = W_w[:, :1024], row stride 2048)
  gemm_nt<<<dim3(G4 / 64, T_STEPS / 64), 256, 0, stream>>>(
      x, IN_DIM, W_w, IN_DIM + HID, W_b, pre, G4, IN_DIM);

  // sequential recurrence over 8192 steps
  lstm_rec<<<NBLK, TPB, 0, stream>>>(W_w, pre, hbuf, hall, bar);

  // y = hall @ out_w^T + out_b
  gemm_nt<<<dim3(OUT_DIM / 64, T_STEPS / 64), 256, 0, stream>>>(
      hall, HID, out_w, OUT_DIM, out_b, out, OUT_DIM, HID);
}

// Round 2
// 37110.553 us; speedup vs baseline: 2.7936x; 2.7936x over previous
//
#include <hip/hip_runtime.h>
#include <hip/hip_bf16.h>
#include <cstdint>
#include <cstddef>

// Problem constants
#define T_STEPS 8192
#define IN_DIM  1024
#define HID     1024
#define OUT_DIM 1024
#define G4      4096   // 4*HID

// Recurrence geometry: 128 blocks x 256 threads = 512 waves,
// each wave owns 2 hidden units (8 W_h rows), 16 weights/lane/row -> w[8][16]
// = 128 persistent VGPRs. No device barrier: tagged-dataflow h exchange.
#define NBLK 128
#define TPB  256
#define UPW  2   // hidden units per wave

__device__ __forceinline__ float sigf(float x) {
  return 1.0f / (1.0f + __expf(-x));
}
__device__ __forceinline__ float tanh_fast(float x) {
  float e = __expf(-2.0f * fabsf(x));
  float t = (1.0f - e) / (1.0f + e);
  return copysignf(t, x);
}

// ---------------------------------------------------------------------------
// GEMM: C[M,N] = A[M,K] @ B[N,K]^T + bias[N]  (64x64 tile, 256 thr, 4x4 micro)
// ---------------------------------------------------------------------------
__global__ __launch_bounds__(256) void gemm_nt(
    const float* __restrict__ A, int lda,
    const float* __restrict__ B, int ldb,
    const float* __restrict__ bias,
    float* __restrict__ C, int ldc,
    int K)
{
  __shared__ float As[16][72];
  __shared__ float Bs[16][72];

  const int tid = threadIdx.x;
  const int m0 = blockIdx.y * 64;
  const int n0 = blockIdx.x * 64;
  const int lr = tid >> 2;
  const int lk = (tid & 3) * 4;
  const int ty = tid >> 4;
  const int tx = tid & 15;

  float acc[4][4];
#pragma unroll
  for (int i = 0; i < 4; ++i)
#pragma unroll
    for (int j = 0; j < 4; ++j) acc[i][j] = 0.0f;

  const float* Ag = A + (size_t)(m0 + lr) * lda + lk;
  const float* Bg = B + (size_t)(n0 + lr) * ldb + lk;

  for (int kt = 0; kt < K; kt += 16) {
    float4 av = *(const float4*)(Ag + kt);
    float4 bv = *(const float4*)(Bg + kt);
    __syncthreads();
    As[lk + 0][lr] = av.x; As[lk + 1][lr] = av.y;
    As[lk + 2][lr] = av.z; As[lk + 3][lr] = av.w;
    Bs[lk + 0][lr] = bv.x; Bs[lk + 1][lr] = bv.y;
    Bs[lk + 2][lr] = bv.z; Bs[lk + 3][lr] = bv.w;
    __syncthreads();
#pragma unroll
    for (int k = 0; k < 16; ++k) {
      float4 a4 = *(const float4*)&As[k][ty * 4];
      float4 b4 = *(const float4*)&Bs[k][tx * 4];
      acc[0][0] = fmaf(a4.x, b4.x, acc[0][0]); acc[0][1] = fmaf(a4.x, b4.y, acc[0][1]);
      acc[0][2] = fmaf(a4.x, b4.z, acc[0][2]); acc[0][3] = fmaf(a4.x, b4.w, acc[0][3]);
      acc[1][0] = fmaf(a4.y, b4.x, acc[1][0]); acc[1][1] = fmaf(a4.y, b4.y, acc[1][1]);
      acc[1][2] = fmaf(a4.y, b4.z, acc[1][2]); acc[1][3] = fmaf(a4.y, b4.w, acc[1][3]);
      acc[2][0] = fmaf(a4.z, b4.x, acc[2][0]); acc[2][1] = fmaf(a4.z, b4.y, acc[2][1]);
      acc[2][2] = fmaf(a4.z, b4.z, acc[2][2]); acc[2][3] = fmaf(a4.z, b4.w, acc[2][3]);
      acc[3][0] = fmaf(a4.w, b4.x, acc[3][0]); acc[3][1] = fmaf(a4.w, b4.y, acc[3][1]);
      acc[3][2] = fmaf(a4.w, b4.z, acc[3][2]); acc[3][3] = fmaf(a4.w, b4.w, acc[3][3]);
    }
  }

  float4 b4 = *(const float4*)(bias + n0 + tx * 4);
#pragma unroll
  for (int i = 0; i < 4; ++i) {
    float4 o;
    o.x = acc[i][0] + b4.x; o.y = acc[i][1] + b4.y;
    o.z = acc[i][2] + b4.z; o.w = acc[i][3] + b4.w;
    *(float4*)(C + (size_t)(m0 + ty * 4 + i) * ldc + n0 + tx * 4) = o;
  }
}

// ---------------------------------------------------------------------------
// Persistent recurrence, barrier-free tagged dataflow.
// hbuf: [2][1024] of u64 {lo=tag, hi=float bits}. Step t reads slot t&1
// expecting tag t; writes h_t into slot (t+1)&1 with tag t+1. Slot 0 memset
// to 0 => tag 0 / h = 0.0 for step 0.
// h element layout interleaved: element e = q*64 + lane (coalesced polls).
// ---------------------------------------------------------------------------
__global__ __launch_bounds__(TPB, 1) void lstm_rec(
    const float* __restrict__ Ww,                 // [4096, 2048]
    const float* __restrict__ pre,                // [T, 4096]
    unsigned long long* __restrict__ hbuf,        // [2][1024] tagged
    float* __restrict__ hall)                     // [T, 1024]
{
  const int lane = threadIdx.x & 63;
  const int wv = blockIdx.x * (TPB / 64) + (threadIdx.x >> 6);  // 0..511
  const int u0 = wv * UPW;

  // Persistent weights: row m = ul*4+g <-> W_w row (g*HID + u0+ul), h-part.
  // Lane's e-slice: e = q*64 + lane  (matches interleaved h layout).
  float w[2 * 4][16];
#pragma unroll
  for (int ul = 0; ul < UPW; ++ul) {
#pragma unroll
    for (int g = 0; g < 4; ++g) {
      const int m = ul * 4 + g;
      const float* wr = Ww + (size_t)(g * HID + u0 + ul) * (IN_DIM + HID) + IN_DIM;
#pragma unroll
      for (int q = 0; q < 16; ++q) w[m][q] = wr[q * 64 + lane];
    }
  }

  float cst0 = 0.0f, cst1 = 0.0f;

  for (int t = 0; t < T_STEPS; ++t) {
    // pre-gates for this wave's units (independent of h -> overlaps poll)
    const float* pr = pre + (size_t)t * G4 + u0;
    float pv00 = pr[0 * HID + 0], pv01 = pr[1 * HID + 0],
          pv02 = pr[2 * HID + 0], pv03 = pr[3 * HID + 0];
    float pv10 = pr[0 * HID + 1], pv11 = pr[1 * HID + 1],
          pv12 = pr[2 * HID + 1], pv13 = pr[3 * HID + 1];

    // Poll h_{t-1}: 16 tagged u64 loads, agent-scope relaxed (bypass XCD L2)
    float hv[16];
    {
      const unsigned long long* hs = hbuf + (size_t)(t & 1) * HID;
      const unsigned want = (unsigned)t;
      for (;;) {
        unsigned long long p[16];
        bool ok = true;
#pragma unroll
        for (int q = 0; q < 16; ++q)
          p[q] = __hip_atomic_load(hs + q * 64 + lane,
                                   __ATOMIC_RELAXED, __HIP_MEMORY_SCOPE_AGENT);
#pragma unroll
        for (int q = 0; q < 16; ++q) ok &= ((unsigned)p[q] == want);
        if (__all((int)ok)) {
#pragma unroll
          for (int q = 0; q < 16; ++q)
            hv[q] = __uint_as_float((unsigned)(p[q] >> 32));
          break;
        }
      }
    }

    // matvec slice: 8 rows x 16 elems
    float acc[8];
#pragma unroll
    for (int m = 0; m < 8; ++m) acc[m] = 0.0f;
#pragma unroll
    for (int q = 0; q < 16; ++q)
#pragma unroll
      for (int m = 0; m < 8; ++m)
        acc[m] = fmaf(w[m][q], hv[q], acc[m]);

    // butterfly reduce across the wave (all lanes end with full row sums)
#pragma unroll
    for (int m = 0; m < 8; ++m) {
      float v = acc[m];
      v += __shfl_xor(v, 1);  v += __shfl_xor(v, 2);  v += __shfl_xor(v, 4);
      v += __shfl_xor(v, 8);  v += __shfl_xor(v, 16); v += __shfl_xor(v, 32);
      acc[m] = v;
    }

    float gi0 = acc[0] + pv00, gf0 = acc[1] + pv01,
          gg0 = acc[2] + pv02, go0 = acc[3] + pv03;
    float gi1 = acc[4] + pv10, gf1 = acc[5] + pv11,
          gg1 = acc[6] + pv12, go1 = acc[7] + pv13;
    cst0 = sigf(gf0) * cst0 + sigf(gi0) * tanh_fast(gg0);
    cst1 = sigf(gf1) * cst1 + sigf(gi1) * tanh_fast(gg1);
    float h0 = sigf(go0) * tanh_fast(cst0);
    float h1 = sigf(go1) * tanh_fast(cst1);

    if (lane < UPW) {
      float val = (lane == 0) ? h0 : h1;
      unsigned long long pk =
          ((unsigned long long)__float_as_uint(val) << 32) | (unsigned)(t + 1);
      __hip_atomic_store(hbuf + (size_t)((t + 1) & 1) * HID + u0 + lane, pk,
                         __ATOMIC_RELAXED, __HIP_MEMORY_SCOPE_AGENT);
      hall[(size_t)t * HID + u0 + lane] = val;
    }
  }
}

// ---------------------------------------------------------------------------
// Workspace layout (bytes):
//   [0, 16K)              : hbuf[2][1024] tagged u64  (memset 0: tag0/h=0)
//   [16K, 16K+33.5MB)     : hall[T][1024]
//   [16K+33.5MB, +134MB)  : pre[T][4096]
// ---------------------------------------------------------------------------
extern "C" void kernel_launch(void* const* d_in, const int* in_sizes, int n_in,
                              void* d_out, int out_size, void* d_ws, size_t ws_size,
                              hipStream_t stream) {
  (void)in_sizes; (void)n_in; (void)out_size; (void)ws_size;

  const float* x     = (const float*)d_in[0];  // [T,1,IN]
  const float* W_w   = (const float*)d_in[1];  // [4096, 2048]
  const float* W_b   = (const float*)d_in[2];  // [4096]
  const float* out_w = (const float*)d_in[3];  // [1024, 1024]
  const float* out_b = (const float*)d_in[4];  // [1024]
  float* out = (float*)d_out;                  // [T,1,1024]

  char* ws = (char*)d_ws;
  unsigned long long* hbuf = (unsigned long long*)ws;
  float* hall = (float*)(ws + 16384);
  float* pre  = (float*)(ws + 16384 + (size_t)T_STEPS * HID * 4);

  hipMemsetAsync(ws, 0, 16384, stream);

  // pre = x @ Wx^T + W_b   (Wx = W_w[:, :1024], row stride 2048)
  gemm_nt<<<dim3(G4 / 64, T_STEPS / 64), 256, 0, stream>>>(
      x, IN_DIM, W_w, IN_DIM + HID, W_b, pre, G4, IN_DIM);

  // sequential recurrence, no barrier
  lstm_rec<<<NBLK, TPB, 0, stream>>>(W_w, pre, hbuf, hall);

  // y = hall @ out_w^T + out_b
  gemm_nt<<<dim3(OUT_DIM / 64, T_STEPS / 64), 256, 0, stream>>>(
      hall, HID, out_w, OUT_DIM, out_b, out, OUT_DIM, HID);
}

// Round 3
// 28558.328 us; speedup vs baseline: 3.6301x; 1.2995x over previous
//
#include <hip/hip_runtime.h>
#include <hip/hip_bf16.h>
#include <cstdint>
#include <cstddef>

// Problem constants
#define T_STEPS 8192
#define IN_DIM  1024
#define HID     1024
#define OUT_DIM 1024
#define G4      4096   // 4*HID

// Recurrence geometry: 64 blocks x 512 threads = 8 waves/block, 512 waves.
// Each wave owns 2 hidden units (8 W_h rows) -> w[8][16] = 128 persistent
// VGPRs/lane. Each BLOCK fetches h once per step (wave j polls slice j into
// LDS), killing the 8x-redundant L3 poll traffic of the previous version.
#define NBLK 64
#define TPB  512
#define WPB  8    // waves per block
#define UPW  2    // hidden units per wave

__device__ __forceinline__ float sigf(float x) {
  return 1.0f / (1.0f + __expf(-x));
}
__device__ __forceinline__ float tanh_fast(float x) {
  float e = __expf(-2.0f * fabsf(x));
  float t = (1.0f - e) / (1.0f + e);
  return copysignf(t, x);
}

// ---------------------------------------------------------------------------
// GEMM: C[M,N] = A[M,K] @ B[N,K]^T + bias[N]  (64x64 tile, 256 thr, 4x4 micro)
// ---------------------------------------------------------------------------
__global__ __launch_bounds__(256) void gemm_nt(
    const float* __restrict__ A, int lda,
    const float* __restrict__ B, int ldb,
    const float* __restrict__ bias,
    float* __restrict__ C, int ldc,
    int K)
{
  __shared__ float As[16][72];
  __shared__ float Bs[16][72];

  const int tid = threadIdx.x;
  const int m0 = blockIdx.y * 64;
  const int n0 = blockIdx.x * 64;
  const int lr = tid >> 2;
  const int lk = (tid & 3) * 4;
  const int ty = tid >> 4;
  const int tx = tid & 15;

  float acc[4][4];
#pragma unroll
  for (int i = 0; i < 4; ++i)
#pragma unroll
    for (int j = 0; j < 4; ++j) acc[i][j] = 0.0f;

  const float* Ag = A + (size_t)(m0 + lr) * lda + lk;
  const float* Bg = B + (size_t)(n0 + lr) * ldb + lk;

  for (int kt = 0; kt < K; kt += 16) {
    float4 av = *(const float4*)(Ag + kt);
    float4 bv = *(const float4*)(Bg + kt);
    __syncthreads();
    As[lk + 0][lr] = av.x; As[lk + 1][lr] = av.y;
    As[lk + 2][lr] = av.z; As[lk + 3][lr] = av.w;
    Bs[lk + 0][lr] = bv.x; Bs[lk + 1][lr] = bv.y;
    Bs[lk + 2][lr] = bv.z; Bs[lk + 3][lr] = bv.w;
    __syncthreads();
#pragma unroll
    for (int k = 0; k < 16; ++k) {
      float4 a4 = *(const float4*)&As[k][ty * 4];
      float4 b4 = *(const float4*)&Bs[k][tx * 4];
      acc[0][0] = fmaf(a4.x, b4.x, acc[0][0]); acc[0][1] = fmaf(a4.x, b4.y, acc[0][1]);
      acc[0][2] = fmaf(a4.x, b4.z, acc[0][2]); acc[0][3] = fmaf(a4.x, b4.w, acc[0][3]);
      acc[1][0] = fmaf(a4.y, b4.x, acc[1][0]); acc[1][1] = fmaf(a4.y, b4.y, acc[1][1]);
      acc[1][2] = fmaf(a4.y, b4.z, acc[1][2]); acc[1][3] = fmaf(a4.y, b4.w, acc[1][3]);
      acc[2][0] = fmaf(a4.z, b4.x, acc[2][0]); acc[2][1] = fmaf(a4.z, b4.y, acc[2][1]);
      acc[2][2] = fmaf(a4.z, b4.z, acc[2][2]); acc[2][3] = fmaf(a4.z, b4.w, acc[2][3]);
      acc[3][0] = fmaf(a4.w, b4.x, acc[3][0]); acc[3][1] = fmaf(a4.w, b4.y, acc[3][1]);
      acc[3][2] = fmaf(a4.w, b4.z, acc[3][2]); acc[3][3] = fmaf(a4.w, b4.w, acc[3][3]);
    }
  }

  float4 b4 = *(const float4*)(bias + n0 + tx * 4);
#pragma unroll
  for (int i = 0; i < 4; ++i) {
    float4 o;
    o.x = acc[i][0] + b4.x; o.y = acc[i][1] + b4.y;
    o.z = acc[i][2] + b4.z; o.w = acc[i][3] + b4.w;
    *(float4*)(C + (size_t)(m0 + ty * 4 + i) * ldc + n0 + tx * 4) = o;
  }
}

// ---------------------------------------------------------------------------
// Persistent recurrence, barrier-free tagged dataflow + per-block LDS staging.
// hbuf: [2][1024] u64 {lo=tag, hi=float bits}. Step t: wave j polls its
// 128-element slice of slot t&1 for tag t, deposits values into LDS slot t&1,
// __syncthreads, all waves read full h from LDS. Producers store h_t with
// tag t+1 into slot (t+1)&1.
// Safety: every block consumes the FULL h each step, so any tag t+1 store
// implies all blocks passed poll t -> device-wide skew <= 1 step -> depth-2
// buffers never skip a tag; LDS parity slots are race-free across the single
// per-step barrier.
// ---------------------------------------------------------------------------
__global__ __launch_bounds__(TPB, 2) void lstm_rec(
    const float* __restrict__ Ww,                 // [4096, 2048]
    const float* __restrict__ pre,                // [T, 4096]
    unsigned long long* __restrict__ hbuf,        // [2][1024] tagged
    float* __restrict__ hall)                     // [T, 1024]
{
  __shared__ float lh[2][HID];

  const int lane = threadIdx.x & 63;
  const int wslot = threadIdx.x >> 6;                 // 0..7
  const int wv = blockIdx.x * WPB + wslot;            // 0..511
  const int u0 = wv * UPW;

  // Persistent weights: row m = ul*4+g <-> W_w row (g*HID + u0+ul), h-part.
  // Lane's e-slice: e = q*64 + lane (matches LDS h layout).
  float w[2 * 4][16];
#pragma unroll
  for (int ul = 0; ul < UPW; ++ul) {
#pragma unroll
    for (int g = 0; g < 4; ++g) {
      const int m = ul * 4 + g;
      const float* wr = Ww + (size_t)(g * HID + u0 + ul) * (IN_DIM + HID) + IN_DIM;
#pragma unroll
      for (int q = 0; q < 16; ++q) w[m][q] = wr[q * 64 + lane];
    }
  }

  float cst0 = 0.0f, cst1 = 0.0f;

  for (int t = 0; t < T_STEPS; ++t) {
    // pre-gates for this wave's units (independent of h -> overlaps poll)
    const float* pr = pre + (size_t)t * G4 + u0;
    float pv00 = pr[0 * HID + 0], pv01 = pr[1 * HID + 0],
          pv02 = pr[2 * HID + 0], pv03 = pr[3 * HID + 0];
    float pv10 = pr[0 * HID + 1], pv11 = pr[1 * HID + 1],
          pv12 = pr[2 * HID + 1], pv13 = pr[3 * HID + 1];

    // Poll my 128-element slice of h_{t-1} (2 tagged u64 loads/lane)
    const unsigned long long* hs = hbuf + (size_t)(t & 1) * HID + wslot * 128;
    const unsigned want = (unsigned)t;
    unsigned long long p0, p1;
    for (;;) {
      p0 = __hip_atomic_load(hs + lane, __ATOMIC_RELAXED, __HIP_MEMORY_SCOPE_AGENT);
      p1 = __hip_atomic_load(hs + 64 + lane, __ATOMIC_RELAXED, __HIP_MEMORY_SCOPE_AGENT);
      bool ok = ((unsigned)p0 == want) & ((unsigned)p1 == want);
      if (__all((int)ok)) break;
    }
    lh[t & 1][wslot * 128 + lane]      = __uint_as_float((unsigned)(p0 >> 32));
    lh[t & 1][wslot * 128 + 64 + lane] = __uint_as_float((unsigned)(p1 >> 32));
    __syncthreads();

    // Full h from LDS (conflict-free: bank = lane%32, 2 lanes/bank)
    float hv[16];
#pragma unroll
    for (int q = 0; q < 16; ++q) hv[q] = lh[t & 1][q * 64 + lane];

    // matvec slice: 8 rows x 16 elems
    float acc[8];
#pragma unroll
    for (int m = 0; m < 8; ++m) acc[m] = 0.0f;
#pragma unroll
    for (int q = 0; q < 16; ++q)
#pragma unroll
      for (int m = 0; m < 8; ++m)
        acc[m] = fmaf(w[m][q], hv[q], acc[m]);

    // butterfly reduce across the wave
#pragma unroll
    for (int m = 0; m < 8; ++m) {
      float v = acc[m];
      v += __shfl_xor(v, 1);  v += __shfl_xor(v, 2);  v += __shfl_xor(v, 4);
      v += __shfl_xor(v, 8);  v += __shfl_xor(v, 16); v += __shfl_xor(v, 32);
      acc[m] = v;
    }

    float gi0 = acc[0] + pv00, gf0 = acc[1] + pv01,
          gg0 = acc[2] + pv02, go0 = acc[3] + pv03;
    float gi1 = acc[4] + pv10, gf1 = acc[5] + pv11,
          gg1 = acc[6] + pv12, go1 = acc[7] + pv13;
    cst0 = sigf(gf0) * cst0 + sigf(gi0) * tanh_fast(gg0);
    cst1 = sigf(gf1) * cst1 + sigf(gi1) * tanh_fast(gg1);
    float h0 = sigf(go0) * tanh_fast(cst0);
    float h1 = sigf(go1) * tanh_fast(cst1);

    if (lane < UPW) {
      float val = (lane == 0) ? h0 : h1;
      unsigned long long pk =
          ((unsigned long long)__float_as_uint(val) << 32) | (unsigned)(t + 1);
      __hip_atomic_store(hbuf + (size_t)((t + 1) & 1) * HID + u0 + lane, pk,
                         __ATOMIC_RELAXED, __HIP_MEMORY_SCOPE_AGENT);
      hall[(size_t)t * HID + u0 + lane] = val;
    }
  }
}

// ---------------------------------------------------------------------------
// Workspace layout (bytes):
//   [0, 16K)              : hbuf[2][1024] tagged u64  (memset 0: tag0/h=0)
//   [16K, 16K+33.5MB)     : hall[T][1024]
//   [16K+33.5MB, +134MB)  : pre[T][4096]
// ---------------------------------------------------------------------------
extern "C" void kernel_launch(void* const* d_in, const int* in_sizes, int n_in,
                              void* d_out, int out_size, void* d_ws, size_t ws_size,
                              hipStream_t stream) {
  (void)in_sizes; (void)n_in; (void)out_size; (void)ws_size;

  const float* x     = (const float*)d_in[0];  // [T,1,IN]
  const float* W_w   = (const float*)d_in[1];  // [4096, 2048]
  const float* W_b   = (const float*)d_in[2];  // [4096]
  const float* out_w = (const float*)d_in[3];  // [1024, 1024]
  const float* out_b = (const float*)d_in[4];  // [1024]
  float* out = (float*)d_out;                  // [T,1,1024]

  char* ws = (char*)d_ws;
  unsigned long long* hbuf = (unsigned long long*)ws;
  float* hall = (float*)(ws + 16384);
  float* pre  = (float*)(ws + 16384 + (size_t)T_STEPS * HID * 4);

  hipMemsetAsync(ws, 0, 16384, stream);

  // pre = x @ Wx^T + W_b   (Wx = W_w[:, :1024], row stride 2048)
  gemm_nt<<<dim3(G4 / 64, T_STEPS / 64), 256, 0, stream>>>(
      x, IN_DIM, W_w, IN_DIM + HID, W_b, pre, G4, IN_DIM);

  // sequential recurrence, no barrier, block-level h staging
  lstm_rec<<<NBLK, TPB, 0, stream>>>(W_w, pre, hbuf, hall);

  // y = hall @ out_w^T + out_b
  gemm_nt<<<dim3(OUT_DIM / 64, T_STEPS / 64), 256, 0, stream>>>(
      hall, HID, out_w, OUT_DIM, out_b, out, OUT_DIM, HID);
}

// Round 4
// 14733.861 us; speedup vs baseline: 7.0362x; 1.9383x over previous
//
#include <hip/hip_runtime.h>
#include <hip/hip_bf16.h>
#include <cstdint>
#include <cstddef>

// Problem constants
#define T_STEPS 8192
#define IN_DIM  1024
#define HID     1024
#define OUT_DIM 1024
#define G4      4096   // 4*HID

// Recurrence geometry: 64 blocks x 512 threads = 8 waves/block, 512 waves.
// Each wave owns 2 hidden units (8 W_h rows). Weights live in EIGHT NAMED
// f32x16 vector registers (128 VGPRs) -- R3's w[8][16] array was silently
// scratch-resident (VGPR_Count=88 < 128), costing 512B/lane scratch reload
// per step. launch_bounds(512,2) -> 256-VGPR cap, plenty.
#define NBLK 64
#define TPB  512
#define WPB  8    // waves per block
#define UPW  2    // hidden units per wave

typedef __attribute__((ext_vector_type(16))) float f32x16;

__device__ __forceinline__ float sigf(float x) {
  return 1.0f / (1.0f + __expf(-x));
}

// Halving reduce step: pair (lane, lane^mask); lane with bit==0 ends with
// row-a total partial, bit==1 with row-b.
__device__ __forceinline__ float halvestep(float a, float b, int mask, int lane) {
  float x = (lane & mask) ? a : b;     // what my partner needs
  float y = __shfl_xor(x, mask);
  return ((lane & mask) ? b : a) + y;
}

// ---------------------------------------------------------------------------
// GEMM: C[M,N] = A[M,K] @ B[N,K]^T + bias[N]  (64x64 tile, 256 thr, 4x4 micro)
// ---------------------------------------------------------------------------
__global__ __launch_bounds__(256) void gemm_nt(
    const float* __restrict__ A, int lda,
    const float* __restrict__ B, int ldb,
    const float* __restrict__ bias,
    float* __restrict__ C, int ldc,
    int K)
{
  __shared__ float As[16][72];
  __shared__ float Bs[16][72];

  const int tid = threadIdx.x;
  const int m0 = blockIdx.y * 64;
  const int n0 = blockIdx.x * 64;
  const int lr = tid >> 2;
  const int lk = (tid & 3) * 4;
  const int ty = tid >> 4;
  const int tx = tid & 15;

  float acc[4][4];
#pragma unroll
  for (int i = 0; i < 4; ++i)
#pragma unroll
    for (int j = 0; j < 4; ++j) acc[i][j] = 0.0f;

  const float* Ag = A + (size_t)(m0 + lr) * lda + lk;
  const float* Bg = B + (size_t)(n0 + lr) * ldb + lk;

  for (int kt = 0; kt < K; kt += 16) {
    float4 av = *(const float4*)(Ag + kt);
    float4 bv = *(const float4*)(Bg + kt);
    __syncthreads();
    As[lk + 0][lr] = av.x; As[lk + 1][lr] = av.y;
    As[lk + 2][lr] = av.z; As[lk + 3][lr] = av.w;
    Bs[lk + 0][lr] = bv.x; Bs[lk + 1][lr] = bv.y;
    Bs[lk + 2][lr] = bv.z; Bs[lk + 3][lr] = bv.w;
    __syncthreads();
#pragma unroll
    for (int k = 0; k < 16; ++k) {
      float4 a4 = *(const float4*)&As[k][ty * 4];
      float4 b4 = *(const float4*)&Bs[k][tx * 4];
      acc[0][0] = fmaf(a4.x, b4.x, acc[0][0]); acc[0][1] = fmaf(a4.x, b4.y, acc[0][1]);
      acc[0][2] = fmaf(a4.x, b4.z, acc[0][2]); acc[0][3] = fmaf(a4.x, b4.w, acc[0][3]);
      acc[1][0] = fmaf(a4.y, b4.x, acc[1][0]); acc[1][1] = fmaf(a4.y, b4.y, acc[1][1]);
      acc[1][2] = fmaf(a4.y, b4.z, acc[1][2]); acc[1][3] = fmaf(a4.y, b4.w, acc[1][3]);
      acc[2][0] = fmaf(a4.z, b4.x, acc[2][0]); acc[2][1] = fmaf(a4.z, b4.y, acc[2][1]);
      acc[2][2] = fmaf(a4.z, b4.z, acc[2][2]); acc[2][3] = fmaf(a4.z, b4.w, acc[2][3]);
      acc[3][0] = fmaf(a4.w, b4.x, acc[3][0]); acc[3][1] = fmaf(a4.w, b4.y, acc[3][1]);
      acc[3][2] = fmaf(a4.w, b4.z, acc[3][2]); acc[3][3] = fmaf(a4.w, b4.w, acc[3][3]);
    }
  }

  float4 b4 = *(const float4*)(bias + n0 + tx * 4);
#pragma unroll
  for (int i = 0; i < 4; ++i) {
    float4 o;
    o.x = acc[i][0] + b4.x; o.y = acc[i][1] + b4.y;
    o.z = acc[i][2] + b4.z; o.w = acc[i][3] + b4.w;
    *(float4*)(C + (size_t)(m0 + ty * 4 + i) * ldc + n0 + tx * 4) = o;
  }
}

// ---------------------------------------------------------------------------
// Persistent recurrence: tagged dataflow (no device barrier) + per-block LDS
// staging + register-resident weights.
// hbuf: [2][1024] u64 {lo=tag, hi=float bits}. Step t: wave j polls its
// 128-elem slice of slot t&1 for tag t -> LDS -> __syncthreads -> full h.
// Row m = ul*4+g of this wave's 8 W_h rows; after the halving reduce, lane l
// holds row (l&7)'s sum. Lane-distributed activations, quad-shuffle gather
// for the c/h update; lanes 0 and 4 publish h for units u0, u0+1.
// ---------------------------------------------------------------------------
__global__ __launch_bounds__(TPB, 2) void lstm_rec(
    const float* __restrict__ Ww,                 // [4096, 2048]
    const float* __restrict__ pre,                // [T, 4096]
    unsigned long long* __restrict__ hbuf,        // [2][1024] tagged
    float* __restrict__ hall)                     // [T, 1024]
{
  __shared__ float lh[2][HID];

  const int lane = threadIdx.x & 63;
  const int wslot = threadIdx.x >> 6;                 // 0..7
  const int wv = blockIdx.x * WPB + wslot;            // 0..511
  const int u0 = wv * UPW;

  // Per-lane gate/unit identity for the post-reduce phase (replicated mod 8)
  const int g  = lane & 3;          // 0:i 1:f 2:g 3:o
  const int ul = (lane >> 2) & 1;   // unit within wave
  const size_t preoff = (size_t)g * HID + u0 + ul;

  // Persistent weights in named vector registers. Row m = ul*4+g.
  // Lane's e-slice: e = q*64 + lane (matches LDS h layout).
  auto loadrow = [&](int gg, int uu) {
    const float* wr = Ww + (size_t)(gg * HID + u0 + uu) * (IN_DIM + HID) + IN_DIM;
    f32x16 v;
#pragma unroll
    for (int q = 0; q < 16; ++q) v[q] = wr[q * 64 + lane];
    return v;
  };
  f32x16 w0 = loadrow(0, 0), w1 = loadrow(1, 0), w2 = loadrow(2, 0), w3 = loadrow(3, 0);
  f32x16 w4 = loadrow(0, 1), w5 = loadrow(1, 1), w6 = loadrow(2, 1), w7 = loadrow(3, 1);

  float c = 0.0f;                      // cell state, replicated per quad
  float pv = pre[preoff];              // pre-gate for step 0 (pipelined)

  for (int t = 0; t < T_STEPS; ++t) {
    // issue next step's pre load now -- a full step of latency cover
    const int tn = (t + 1 < T_STEPS) ? (t + 1) : t;
    const float pv_next = pre[(size_t)tn * G4 + preoff];

    // Poll my 128-element slice of h_{t-1} (2 tagged u64 loads/lane)
    const unsigned long long* hs = hbuf + (size_t)(t & 1) * HID + wslot * 128;
    const unsigned want = (unsigned)t;
    unsigned long long p0, p1;
    for (;;) {
      p0 = __hip_atomic_load(hs + lane, __ATOMIC_RELAXED, __HIP_MEMORY_SCOPE_AGENT);
      p1 = __hip_atomic_load(hs + 64 + lane, __ATOMIC_RELAXED, __HIP_MEMORY_SCOPE_AGENT);
      bool ok = ((unsigned)p0 == want) & ((unsigned)p1 == want);
      if (__all((int)ok)) break;
    }
    lh[t & 1][wslot * 128 + lane]      = __uint_as_float((unsigned)(p0 >> 32));
    lh[t & 1][wslot * 128 + 64 + lane] = __uint_as_float((unsigned)(p1 >> 32));
    __syncthreads();

    // Full h from LDS (bank = lane%32, 2 lanes/bank: free)
    float hv[16];
#pragma unroll
    for (int q = 0; q < 16; ++q) hv[q] = lh[t & 1][q * 64 + lane];

    // matvec: 8 rows x 16 elems, weights in VGPRs
    float a0 = 0, a1 = 0, a2 = 0, a3 = 0, a4 = 0, a5 = 0, a6 = 0, a7 = 0;
#pragma unroll
    for (int q = 0; q < 16; ++q) {
      const float h = hv[q];
      a0 = fmaf(w0[q], h, a0); a1 = fmaf(w1[q], h, a1);
      a2 = fmaf(w2[q], h, a2); a3 = fmaf(w3[q], h, a3);
      a4 = fmaf(w4[q], h, a4); a5 = fmaf(w5[q], h, a5);
      a6 = fmaf(w6[q], h, a6); a7 = fmaf(w7[q], h, a7);
    }

    // Halving reduce: 7 shuffles to land row (lane&7) in lane, then 3 full
    // butterflies over the remaining lane bits.
    float r0 = halvestep(a0, a1, 1, lane);
    float r1 = halvestep(a2, a3, 1, lane);
    float r2 = halvestep(a4, a5, 1, lane);
    float r3 = halvestep(a6, a7, 1, lane);
    float s0 = halvestep(r0, r1, 2, lane);
    float s1 = halvestep(r2, r3, 2, lane);
    float u  = halvestep(s0, s1, 4, lane);
    u += __shfl_xor(u, 8); u += __shfl_xor(u, 16); u += __shfl_xor(u, 32);
    // lane l now holds the full sum for row m = l&7 (gate g=m&3, unit m>>2)

    const float gv = u + pv;
    // gate activation: sigmoid for i,f,o; tanh for g via 2*sig(2x)-1
    const bool isg = (g == 2);
    const float s = sigf(isg ? 2.0f * gv : gv);
    const float act = isg ? fmaf(2.0f, s, -1.0f) : s;

    // gather my quad's four gate activations
    const int base = lane & ~3;
    const float si = __shfl(act, base);
    const float sf = __shfl(act, base | 1);
    const float tg = __shfl(act, base | 2);
    const float so = __shfl(act, base | 3);

    c = fmaf(sf, c, si * tg);
    const float s2 = sigf(2.0f * c);
    const float h = so * fmaf(2.0f, s2, -1.0f);   // so * tanh(c)

    if (lane < 8 && (lane & 3) == 0) {
      const int unit = u0 + (lane >> 2);
      unsigned long long pk =
          ((unsigned long long)__float_as_uint(h) << 32) | (unsigned)(t + 1);
      __hip_atomic_store(hbuf + (size_t)((t + 1) & 1) * HID + unit, pk,
                         __ATOMIC_RELAXED, __HIP_MEMORY_SCOPE_AGENT);
      hall[(size_t)t * HID + unit] = h;
    }

    pv = pv_next;
  }
}

// ---------------------------------------------------------------------------
// Workspace layout (bytes):
//   [0, 16K)              : hbuf[2][1024] tagged u64  (memset 0: tag0/h=0)
//   [16K, 16K+33.5MB)     : hall[T][1024]
//   [16K+33.5MB, +134MB)  : pre[T][4096]
// ---------------------------------------------------------------------------
extern "C" void kernel_launch(void* const* d_in, const int* in_sizes, int n_in,
                              void* d_out, int out_size, void* d_ws, size_t ws_size,
                              hipStream_t stream) {
  (void)in_sizes; (void)n_in; (void)out_size; (void)ws_size;

  const float* x     = (const float*)d_in[0];  // [T,1,IN]
  const float* W_w   = (const float*)d_in[1];  // [4096, 2048]
  const float* W_b   = (const float*)d_in[2];  // [4096]
  const float* out_w = (const float*)d_in[3];  // [1024, 1024]
  const float* out_b = (const float*)d_in[4];  // [1024]
  float* out = (float*)d_out;                  // [T,1,1024]

  char* ws = (char*)d_ws;
  unsigned long long* hbuf = (unsigned long long*)ws;
  float* hall = (float*)(ws + 16384);
  float* pre  = (float*)(ws + 16384 + (size_t)T_STEPS * HID * 4);

  hipMemsetAsync(ws, 0, 16384, stream);

  // pre = x @ Wx^T + W_b   (Wx = W_w[:, :1024], row stride 2048)
  gemm_nt<<<dim3(G4 / 64, T_STEPS / 64), 256, 0, stream>>>(
      x, IN_DIM, W_w, IN_DIM + HID, W_b, pre, G4, IN_DIM);

  // sequential recurrence, no barrier, block-level h staging
  lstm_rec<<<NBLK, TPB, 0, stream>>>(W_w, pre, hbuf, hall);

  // y = hall @ out_w^T + out_b
  gemm_nt<<<dim3(OUT_DIM / 64, T_STEPS / 64), 256, 0, stream>>>(
      hall, HID, out_w, OUT_DIM, out_b, out, OUT_DIM, HID);
}